// Round 15
// baseline (433.217 us; speedup 1.0000x reference)
//
#include <hip/hip_runtime.h>
#include <hip/hip_bf16.h>

#define S_LEN 2048
#define BATCH 2
#define DMODEL 1024
#define NHEAD 16
#define HDIM 64
#define MTOT (S_LEN * BATCH)
#define QKV_ELEMS ((size_t)MTOT * DMODEL)          // 4194304
#define XOFF (3 * QKV_ELEMS)                       // bf16 X' segment base (ushorts)
#define WOFF (XOFF + 3 * QKV_ELEMS)                // bf16 W' segment base
#define WSEG ((size_t)DMODEL * DMODEL)             // 1048576

typedef __bf16 bf16x8 __attribute__((ext_vector_type(8)));
typedef unsigned short u16x8 __attribute__((ext_vector_type(8)));
typedef float f32x4 __attribute__((ext_vector_type(4)));
typedef float f32x16 __attribute__((ext_vector_type(16)));
typedef unsigned int u32x4 __attribute__((ext_vector_type(4)));

__device__ __forceinline__ unsigned short f2bf(float f) {
    unsigned int u = __float_as_uint(f);
    u += 0x7FFFu + ((u >> 16) & 1u);
    return (unsigned short)(u >> 16);
}

// compiler-emitted v_cvt_pk_bf16_f32 (m240: do NOT hand-asm this).
__device__ __forceinline__ unsigned int pack2(float lo, float hi) {
    __hip_bfloat162 h = __float22bfloat162_rn(make_float2(lo, hi));
    unsigned int r;
    __builtin_memcpy(&r, &h, 4);
    return r;
}

__device__ __forceinline__ void gload_lds16(const void* g, void* l) {
    __builtin_amdgcn_global_load_lds(
        (const __attribute__((address_space(1))) unsigned int*)g,
        (__attribute__((address_space(3))) unsigned int*)l, 16, 0, 0);
}

// ---------------------------------------------------------------------------
// cvt_kernel (frozen): fp32 -> bf16 for X and W into ws.
// ---------------------------------------------------------------------------
__global__ __launch_bounds__(256) void cvt_kernel(
        const float* __restrict__ Xq, const float* __restrict__ Xk,
        const float* __restrict__ Xv, const float* __restrict__ Wq,
        const float* __restrict__ Wk, const float* __restrict__ Wv,
        unsigned short* __restrict__ ws)
{
    const int seg = blockIdx.y;
    const float* src;
    unsigned short* dst;
    int n4;
    if (seg < 3) {
        src = (seg == 0) ? Xq : (seg == 1) ? Xk : Xv;
        dst = ws + XOFF + (size_t)seg * QKV_ELEMS;
        n4  = (int)(QKV_ELEMS / 4);
    } else {
        const int s = seg - 3;
        src = (s == 0) ? Wq : (s == 1) ? Wk : Wv;
        dst = ws + WOFF + (size_t)s * WSEG;
        n4  = (int)(WSEG / 4);
    }
    const int stride = gridDim.x * blockDim.x;
    for (int i = blockIdx.x * blockDim.x + threadIdx.x; i < n4; i += stride) {
        const float4 v = ((const float4*)src)[i];
        uint2 o;
        o.x = pack2(v.x, v.y);
        o.y = pack2(v.z, v.w);
        ((uint2*)dst)[i] = o;
    }
}

// ---------------------------------------------------------------------------
// Projection GEMM (frozen — m97 structure on pre-converted bf16).
// Q: [b][h][s][d] scaled by 0.125*log2(e).  K: [b][h][s][d].  V: [b][h][d][s].
// ---------------------------------------------------------------------------
#define PBM 128
#define PBN 128
#define PBK 32
#define QSCALE 0.18033688011112042f   // 0.125 * log2(e)

__global__ __launch_bounds__(256, 3) void proj_kernel(
        const unsigned short* __restrict__ wsin,
        const float* __restrict__ bq, const float* __restrict__ bk,
        const float* __restrict__ bv, unsigned short* __restrict__ wsout)
{
    const int work = (blockIdx.x & 7) * 96 + (blockIdx.x >> 3);   // 0..767
    const int t    = work >> 8;
    const int rem  = work & 255;
    const int m0   = (rem >> 3) * PBM;
    const int n0   = (rem & 7) * PBN;

    const unsigned short* X = wsin + XOFF + (size_t)t * QKV_ELEMS;
    const unsigned short* W = wsin + WOFF + (size_t)t * WSEG;
    const float* bias = (t == 0) ? bq : (t == 1) ? bk : bv;
    unsigned short* out = wsout + (size_t)t * QKV_ELEMS;
    const float scale = (t == 0) ? QSCALE : 1.0f;

    __shared__ __align__(16) unsigned short Abuf[2][PBM * PBK];
    __shared__ __align__(16) unsigned short Bbuf[2][PBN * PBK];

    const int tid  = threadIdx.x;
    const int wave = tid >> 6;
    const int lane = tid & 63;
    const int lrow = lane & 15;
    const int lg   = lane >> 4;
    const int wr = (wave >> 1) * 64;
    const int wc = (wave & 1) * 64;

    f32x4 acc[4][4];
#pragma unroll
    for (int i = 0; i < 4; ++i)
#pragma unroll
        for (int j = 0; j < 4; ++j)
            acc[i][j] = (f32x4){0.f, 0.f, 0.f, 0.f};

    const int srow_ = tid >> 2;
    const int sc_   = tid & 3;
    const int gsw = (lg ^ (lrow & 3)) * 8;

#pragma unroll
    for (int i0 = 0; i0 < 2; ++i0) {
        const int row = i0 * 64 + srow_;
        const int c   = sc_ ^ (row & 3);
        gload_lds16(X + (size_t)(m0 + row) * DMODEL + c * 8, &Abuf[0][i0 * 2048 + tid * 8]);
        gload_lds16(W + (size_t)(n0 + row) * DMODEL + c * 8, &Bbuf[0][i0 * 2048 + tid * 8]);
    }
    __syncthreads();

    int cur = 0;
    for (int k0 = 0; k0 < DMODEL; k0 += PBK) {
        if (k0 + PBK < DMODEL) {
#pragma unroll
            for (int i0 = 0; i0 < 2; ++i0) {
                const int row = i0 * 64 + srow_;
                const int c   = sc_ ^ (row & 3);
                gload_lds16(X + (size_t)(m0 + row) * DMODEL + k0 + PBK + c * 8,
                            &Abuf[cur ^ 1][i0 * 2048 + tid * 8]);
                gload_lds16(W + (size_t)(n0 + row) * DMODEL + k0 + PBK + c * 8,
                            &Bbuf[cur ^ 1][i0 * 2048 + tid * 8]);
            }
        }

        bf16x8 af[4], bw[4];
#pragma unroll
        for (int i = 0; i < 4; ++i) {
            af[i] = *(const bf16x8*)&Abuf[cur][(wr + i * 16 + lrow) * PBK + gsw];
            bw[i] = *(const bf16x8*)&Bbuf[cur][(wc + i * 16 + lrow) * PBK + gsw];
        }
        __builtin_amdgcn_s_setprio(1);
#pragma unroll
        for (int i = 0; i < 4; ++i)
#pragma unroll
            for (int j = 0; j < 4; ++j)
                acc[i][j] = __builtin_amdgcn_mfma_f32_16x16x32_bf16(af[i], bw[j], acc[i][j], 0, 0, 0);
        __builtin_amdgcn_s_setprio(0);

        __syncthreads();
        cur ^= 1;
    }

#pragma unroll
    for (int j = 0; j < 4; ++j) {
        const int n  = n0 + wc + j * 16 + lrow;
        const float bv_ = bias[n];
        const int h  = n >> 6;
        const int dd = n & 63;
#pragma unroll
        for (int i = 0; i < 4; ++i) {
#pragma unroll
            for (int r = 0; r < 4; ++r) {
                const int m = m0 + wr + i * 16 + lg * 4 + r;
                const int s = m >> 1;
                const int b = m & 1;
                const float v = (acc[i][j][r] + bv_) * scale;
                size_t idx;
                if (t == 2)
                    idx = ((size_t)((b * NHEAD + h) * HDIM + dd)) * S_LEN + s;
                else
                    idx = ((size_t)((b * NHEAD + h) * S_LEN + s)) * HDIM + dd;
                out[idx] = f2bf(v);
            }
        }
    }
}

// ---------------------------------------------------------------------------
// Flash attention, KV-parity split, 8-wave blocks (occupancy fix for R13):
//   512 blocks x 512 thr.  Block = 128 q (4 qsub x 32q) x full KV; per qsub
//   two parity waves split the 32-key tiles and merge at the end (exact).
//   K/V staged ONCE per block (waves 0-3 stage tile 2p+2, waves 4-7 tile
//   2p+3; 1 gload K + 1 gload V per thread per period).  4-deep ring,
//   ONE barrier/period.  LDS = 16K(K)+16K(V)+16K(Pu) = 48KB -> 3 blocks/CU
//   = 24 waves/CU (75% cap).  Per-tile math byte-identical to R13 (passed).
// ---------------------------------------------------------------------------
#define NP 32   // periods (64 keys each)

__global__ __launch_bounds__(512, 6) void attn_kernel(
        const unsigned short* __restrict__ ws, float* __restrict__ out)
{
    const unsigned short* Qw = ws;
    const unsigned short* Kw = ws + QKV_ELEMS;
    const unsigned short* Vw = ws + 2 * QKV_ELEMS;   // [b][h][d][s]

    // 512 blocks: 4 bh per XCD, 16 q-chunks of 128 per bh
    const int bid = blockIdx.x;
    const int idx = bid >> 3;                        // 0..63
    const int bh  = (bid & 7) * 4 + (idx >> 4);      // 0..31
    const int q0  = (idx & 15) * 128;

    // SMEM carve: K 4x2048 ush | V 4x2048 ush | Pu 8x512 u32 = 49152 B
    __shared__ __align__(16) unsigned short SMEM[24576];
    unsigned short* Kb = SMEM;               // + (t&3)*2048
    unsigned short* Vb = SMEM + 8192;        // + (t&3)*2048
    unsigned int*   Pb = (unsigned int*)(SMEM + 16384);

    const int tid  = threadIdx.x;
    const int wave = tid >> 6;                       // 0..7
    const int lane = tid & 63;
    const int l31  = lane & 31;
    const int half = lane >> 5;
    const int qsub = wave >> 1;                      // 0..3
    const int pw   = wave & 1;                       // KV parity

    const size_t base = (size_t)bh * S_LEN * HDIM;
    const int qrow = q0 + qsub * 32 + l31;

    // Q^T B-frags: lane = q-col l31, d-slots c*16 + half*8 + j
    bf16x8 qf[4];
#pragma unroll
    for (int c = 0; c < 4; ++c)
        qf[c] = *(const bf16x8*)(Qw + base + (size_t)qrow * HDIM + c * 16 + half * 8);

    bf16x8 ones;
    {
        u16x8 o;
#pragma unroll
        for (int e = 0; e < 8; ++e) o[e] = 0x3F80;
        ones = __builtin_bit_cast(bf16x8, o);
    }

    f32x16 Od0, Od1, Lacc;
#pragma unroll
    for (int i = 0; i < 16; ++i) { Od0[i] = 0.f; Od1[i] = 0.f; Lacc[i] = 0.f; }
    float mrun = -__builtin_inff();

    unsigned int* PuW = Pb + wave * 512;             // 16 rows x 32 q

    // staging coords: 512 threads cover 2 tiles (tid>>8 selects which).
    // K tile = [32 keys][64 d]; V tile = [64 d][32 s].
    const int stile = tid >> 8;                      // 0 or 1 (wave-uniform)
    const int t256  = tid & 255;
    const int ksrow = t256 >> 3;                     // 0..31
    const int ksg   = (t256 & 7) ^ (ksrow & 7);
    const int vrow  = t256 >> 2;                     // 0..63
    const int vsg   = (t256 & 3) ^ ((vrow >> 1) & 3);

    // hoisted read-side swizzled offsets
    int gk[4], gv[2];
#pragma unroll
    for (int c = 0; c < 4; ++c) gk[c] = ((c * 2 + half) ^ (l31 & 7)) * 8;
#pragma unroll
    for (int c = 0; c < 2; ++c) gv[c] = ((c * 2 + half) ^ ((l31 >> 1) & 3)) * 8;

    // prologue: stage tiles 0,1 (tile tt = stile)
    {
        const int tt = stile;
        gload_lds16(Kw + base + (size_t)(tt * 32 + ksrow) * HDIM + ksg * 8, &Kb[(tt & 3) * 2048 + t256 * 8]);
        gload_lds16(Vw + base + (size_t)vrow * S_LEN + tt * 32 + vsg * 8,   &Vb[(tt & 3) * 2048 + t256 * 8]);
    }
    __syncthreads();

    for (int p = 0; p < NP; ++p) {
        if (p < NP - 1) {
            const int tt = 2 * p + 2 + stile;
            gload_lds16(Kw + base + (size_t)(tt * 32 + ksrow) * HDIM + ksg * 8, &Kb[(tt & 3) * 2048 + t256 * 8]);
            gload_lds16(Vw + base + (size_t)vrow * S_LEN + tt * 32 + vsg * 8,   &Vb[(tt & 3) * 2048 + t256 * 8]);
        }

        const int tm = 2 * p + pw;                   // my parity's tile
        const unsigned short* Klds = &Kb[(tm & 3) * 2048];
        const unsigned short* Vlds = &Vb[(tm & 3) * 2048];

        // ---- QK: S^T = K(32 keys) . Q^T over d=64 ----
        f32x16 S;
#pragma unroll
        for (int i = 0; i < 16; ++i) S[i] = 0.f;
        __builtin_amdgcn_s_setprio(1);
#pragma unroll
        for (int c = 0; c < 4; ++c) {
            const bf16x8 ka = *(const bf16x8*)&Klds[l31 * 64 + gk[c]];
            S = __builtin_amdgcn_mfma_f32_32x32x16_bf16(ka, qf[c], S, 0, 0, 0);
        }
        __builtin_amdgcn_s_setprio(0);

        // ---- in-reg softmax (base 2), defer-max THR=8 ----
        float m8[8], m4[4];
#pragma unroll
        for (int i = 0; i < 8; ++i) m8[i] = fmaxf(S[i], S[i + 8]);
#pragma unroll
        for (int i = 0; i < 4; ++i) m4[i] = fmaxf(m8[i], m8[i + 4]);
        float mx = fmaxf(fmaxf(m4[0], m4[1]), fmaxf(m4[2], m4[3]));
        mx = fmaxf(mx, __shfl_xor(mx, 32, 64));      // other 16 keys

        if (!__all(mx - mrun <= 8.0f)) {
            const float mnew = fmaxf(mrun, mx);
            const float ex   = exp2f(mrun - mnew);
            mrun = mnew;
            Od0 *= ex;
            Od1 *= ex;
            Lacc *= ex;
        }

#pragma unroll
        for (int i = 0; i < 16; ++i) S[i] = exp2f(S[i] - mrun);

        // ---- P^T -> Pu key-pairs (C/D layout m74/m101: key=(r&3)+8(r>>2)+4h) ----
#pragma unroll
        for (int w = 0; w < 8; ++w) {
            const unsigned int pk = pack2(S[2 * w], S[2 * w + 1]);
            const int kp = (w & 1) + 4 * (w >> 1) + 2 * half;
            PuW[kp * 32 + l31] = pk;
        }
        __asm__ volatile("" ::: "memory");

        // ---- PV: O^T[d][q] += V^T.P^T ; Lacc += ones.P^T (k = 32 keys) ----
        __builtin_amdgcn_s_setprio(1);
#pragma unroll
        for (int c = 0; c < 2; ++c) {
            u32x4 pu;
#pragma unroll
            for (int e = 0; e < 4; ++e)
                pu[e] = PuW[(c * 8 + half * 4 + e) * 32 + l31];
            const bf16x8 pb = __builtin_bit_cast(bf16x8, pu);
            const bf16x8 va0 = *(const bf16x8*)&Vlds[l31 * 32 + gv[c]];
            const bf16x8 va1 = *(const bf16x8*)&Vlds[(32 + l31) * 32 + gv[c]];
            Od0  = __builtin_amdgcn_mfma_f32_32x32x16_bf16(va0,  pb, Od0,  0, 0, 0);
            Od1  = __builtin_amdgcn_mfma_f32_32x32x16_bf16(va1,  pb, Od1,  0, 0, 0);
            Lacc = __builtin_amdgcn_mfma_f32_32x32x16_bf16(ones, pb, Lacc, 0, 0, 0);
        }
        __builtin_amdgcn_s_setprio(0);

        __syncthreads();   // drains stage loads; rotates buffers
    }

    // ---- merge parity partials (exact): wave pair (qsub), lane-wise ----
    float* mrg = (float*)SMEM;                       // overlay (K/V dead)
    float* reg = mrg + qsub * 2176;                  // 64 m + 64 l + 2048 O
    if (pw) {
        reg[lane]      = mrun;
        reg[64 + lane] = Lacc[0];
#pragma unroll
        for (int i = 0; i < 16; ++i) {
            reg[128 + i * 64 + lane]        = Od0[i];
            reg[128 + (16 + i) * 64 + lane] = Od1[i];
        }
    }
    __syncthreads();
    if (!pw) {
        const float mb = reg[lane];
        const float lb = reg[64 + lane];
        const float ms = fmaxf(mrun, mb);
        const float sa = exp2f(mrun - ms);
        const float sb = exp2f(mb - ms);
        const float linv = 1.0f / (Lacc[0] * sa + lb * sb);

        const int bb = bh >> 4;
        const int hh = bh & 15;
        float* op = out + (size_t)qrow * (BATCH * DMODEL) + bb * DMODEL + hh * HDIM;
#pragma unroll
        for (int gg = 0; gg < 4; ++gg) {
            const int d0 = gg * 8 + half * 4;
            float4 v0, v1;
            v0.x = (Od0[gg * 4 + 0] * sa + reg[128 + (gg * 4 + 0) * 64 + lane] * sb) * linv;
            v0.y = (Od0[gg * 4 + 1] * sa + reg[128 + (gg * 4 + 1) * 64 + lane] * sb) * linv;
            v0.z = (Od0[gg * 4 + 2] * sa + reg[128 + (gg * 4 + 2) * 64 + lane] * sb) * linv;
            v0.w = (Od0[gg * 4 + 3] * sa + reg[128 + (gg * 4 + 3) * 64 + lane] * sb) * linv;
            v1.x = (Od1[gg * 4 + 0] * sa + reg[128 + (16 + gg * 4 + 0) * 64 + lane] * sb) * linv;
            v1.y = (Od1[gg * 4 + 1] * sa + reg[128 + (16 + gg * 4 + 1) * 64 + lane] * sb) * linv;
            v1.z = (Od1[gg * 4 + 2] * sa + reg[128 + (16 + gg * 4 + 2) * 64 + lane] * sb) * linv;
            v1.w = (Od1[gg * 4 + 3] * sa + reg[128 + (16 + gg * 4 + 3) * 64 + lane] * sb) * linv;
            *(float4*)(op + d0)      = v0;
            *(float4*)(op + 32 + d0) = v1;
        }
    }
}

extern "C" void kernel_launch(void* const* d_in, const int* in_sizes, int n_in,
                              void* d_out, int out_size, void* d_ws, size_t ws_size,
                              hipStream_t stream) {
    const float* q  = (const float*)d_in[0];
    const float* k  = (const float*)d_in[1];
    const float* v  = (const float*)d_in[2];
    const float* Wq = (const float*)d_in[3];
    const float* bq = (const float*)d_in[4];
    const float* Wk = (const float*)d_in[5];
    const float* bk = (const float*)d_in[6];
    const float* Wv = (const float*)d_in[7];
    const float* bv = (const float*)d_in[8];
    unsigned short* ws = (unsigned short*)d_ws;
    float* out = (float*)d_out;

    cvt_kernel<<<dim3(1024, 6), dim3(256), 0, stream>>>(q, k, v, Wq, Wk, Wv, ws);
    proj_kernel<<<dim3(768), dim3(256), 0, stream>>>(ws, bq, bk, bv, ws);
    attn_kernel<<<dim3(512), dim3(512), 0, stream>>>(ws, out);
}

// Round 16
// 134.236 us; speedup vs baseline: 3.2273x; 3.2273x over previous
//
#include <hip/hip_runtime.h>
#include <hip/hip_bf16.h>

#define S_LEN 2048
#define BATCH 2
#define DMODEL 1024
#define NHEAD 16
#define HDIM 64
#define MTOT (S_LEN * BATCH)
#define QKV_ELEMS ((size_t)MTOT * DMODEL)          // 4194304
#define XOFF (3 * QKV_ELEMS)                       // bf16 X' segment base (ushorts)
#define WOFF (XOFF + 3 * QKV_ELEMS)                // bf16 W' segment base
#define WSEG ((size_t)DMODEL * DMODEL)             // 1048576

typedef __bf16 bf16x8 __attribute__((ext_vector_type(8)));
typedef unsigned short u16x8 __attribute__((ext_vector_type(8)));
typedef float f32x4 __attribute__((ext_vector_type(4)));
typedef float f32x16 __attribute__((ext_vector_type(16)));
typedef unsigned int u32x4 __attribute__((ext_vector_type(4)));

__device__ __forceinline__ unsigned short f2bf(float f) {
    unsigned int u = __float_as_uint(f);
    u += 0x7FFFu + ((u >> 16) & 1u);
    return (unsigned short)(u >> 16);
}

// compiler-emitted v_cvt_pk_bf16_f32 (m240: do NOT hand-asm this).
__device__ __forceinline__ unsigned int pack2(float lo, float hi) {
    __hip_bfloat162 h = __float22bfloat162_rn(make_float2(lo, hi));
    unsigned int r;
    __builtin_memcpy(&r, &h, 4);
    return r;
}

__device__ __forceinline__ void gload_lds16(const void* g, void* l) {
    __builtin_amdgcn_global_load_lds(
        (const __attribute__((address_space(1))) unsigned int*)g,
        (__attribute__((address_space(3))) unsigned int*)l, 16, 0, 0);
}

// ---------------------------------------------------------------------------
// cvt_kernel (frozen): fp32 -> bf16 for X and W into ws.
// ---------------------------------------------------------------------------
__global__ __launch_bounds__(256) void cvt_kernel(
        const float* __restrict__ Xq, const float* __restrict__ Xk,
        const float* __restrict__ Xv, const float* __restrict__ Wq,
        const float* __restrict__ Wk, const float* __restrict__ Wv,
        unsigned short* __restrict__ ws)
{
    const int seg = blockIdx.y;
    const float* src;
    unsigned short* dst;
    int n4;
    if (seg < 3) {
        src = (seg == 0) ? Xq : (seg == 1) ? Xk : Xv;
        dst = ws + XOFF + (size_t)seg * QKV_ELEMS;
        n4  = (int)(QKV_ELEMS / 4);
    } else {
        const int s = seg - 3;
        src = (s == 0) ? Wq : (s == 1) ? Wk : Wv;
        dst = ws + WOFF + (size_t)s * WSEG;
        n4  = (int)(WSEG / 4);
    }
    const int stride = gridDim.x * blockDim.x;
    for (int i = blockIdx.x * blockDim.x + threadIdx.x; i < n4; i += stride) {
        const float4 v = ((const float4*)src)[i];
        uint2 o;
        o.x = pack2(v.x, v.y);
        o.y = pack2(v.z, v.w);
        ((uint2*)dst)[i] = o;
    }
}

// ---------------------------------------------------------------------------
// Projection GEMM (frozen — m97 structure on pre-converted bf16).
// Q: [b][h][s][d] scaled by 0.125*log2(e).  K: [b][h][s][d].  V: [b][h][d][s].
// ---------------------------------------------------------------------------
#define PBM 128
#define PBN 128
#define PBK 32
#define QSCALE 0.18033688011112042f   // 0.125 * log2(e)

__global__ __launch_bounds__(256, 3) void proj_kernel(
        const unsigned short* __restrict__ wsin,
        const float* __restrict__ bq, const float* __restrict__ bk,
        const float* __restrict__ bv, unsigned short* __restrict__ wsout)
{
    const int work = (blockIdx.x & 7) * 96 + (blockIdx.x >> 3);   // 0..767
    const int t    = work >> 8;
    const int rem  = work & 255;
    const int m0   = (rem >> 3) * PBM;
    const int n0   = (rem & 7) * PBN;

    const unsigned short* X = wsin + XOFF + (size_t)t * QKV_ELEMS;
    const unsigned short* W = wsin + WOFF + (size_t)t * WSEG;
    const float* bias = (t == 0) ? bq : (t == 1) ? bk : bv;
    unsigned short* out = wsout + (size_t)t * QKV_ELEMS;
    const float scale = (t == 0) ? QSCALE : 1.0f;

    __shared__ __align__(16) unsigned short Abuf[2][PBM * PBK];
    __shared__ __align__(16) unsigned short Bbuf[2][PBN * PBK];

    const int tid  = threadIdx.x;
    const int wave = tid >> 6;
    const int lane = tid & 63;
    const int lrow = lane & 15;
    const int lg   = lane >> 4;
    const int wr = (wave >> 1) * 64;
    const int wc = (wave & 1) * 64;

    f32x4 acc[4][4];
#pragma unroll
    for (int i = 0; i < 4; ++i)
#pragma unroll
        for (int j = 0; j < 4; ++j)
            acc[i][j] = (f32x4){0.f, 0.f, 0.f, 0.f};

    const int srow_ = tid >> 2;
    const int sc_   = tid & 3;
    const int gsw = (lg ^ (lrow & 3)) * 8;

#pragma unroll
    for (int i0 = 0; i0 < 2; ++i0) {
        const int row = i0 * 64 + srow_;
        const int c   = sc_ ^ (row & 3);
        gload_lds16(X + (size_t)(m0 + row) * DMODEL + c * 8, &Abuf[0][i0 * 2048 + tid * 8]);
        gload_lds16(W + (size_t)(n0 + row) * DMODEL + c * 8, &Bbuf[0][i0 * 2048 + tid * 8]);
    }
    __syncthreads();

    int cur = 0;
    for (int k0 = 0; k0 < DMODEL; k0 += PBK) {
        if (k0 + PBK < DMODEL) {
#pragma unroll
            for (int i0 = 0; i0 < 2; ++i0) {
                const int row = i0 * 64 + srow_;
                const int c   = sc_ ^ (row & 3);
                gload_lds16(X + (size_t)(m0 + row) * DMODEL + k0 + PBK + c * 8,
                            &Abuf[cur ^ 1][i0 * 2048 + tid * 8]);
                gload_lds16(W + (size_t)(n0 + row) * DMODEL + k0 + PBK + c * 8,
                            &Bbuf[cur ^ 1][i0 * 2048 + tid * 8]);
            }
        }

        bf16x8 af[4], bw[4];
#pragma unroll
        for (int i = 0; i < 4; ++i) {
            af[i] = *(const bf16x8*)&Abuf[cur][(wr + i * 16 + lrow) * PBK + gsw];
            bw[i] = *(const bf16x8*)&Bbuf[cur][(wc + i * 16 + lrow) * PBK + gsw];
        }
        __builtin_amdgcn_s_setprio(1);
#pragma unroll
        for (int i = 0; i < 4; ++i)
#pragma unroll
            for (int j = 0; j < 4; ++j)
                acc[i][j] = __builtin_amdgcn_mfma_f32_16x16x32_bf16(af[i], bw[j], acc[i][j], 0, 0, 0);
        __builtin_amdgcn_s_setprio(0);

        __syncthreads();
        cur ^= 1;
    }

#pragma unroll
    for (int j = 0; j < 4; ++j) {
        const int n  = n0 + wc + j * 16 + lrow;
        const float bv_ = bias[n];
        const int h  = n >> 6;
        const int dd = n & 63;
#pragma unroll
        for (int i = 0; i < 4; ++i) {
#pragma unroll
            for (int r = 0; r < 4; ++r) {
                const int m = m0 + wr + i * 16 + lg * 4 + r;
                const int s = m >> 1;
                const int b = m & 1;
                const float v = (acc[i][j][r] + bv_) * scale;
                size_t idx;
                if (t == 2)
                    idx = ((size_t)((b * NHEAD + h) * HDIM + dd)) * S_LEN + s;
                else
                    idx = ((size_t)((b * NHEAD + h) * S_LEN + s)) * HDIM + dd;
                out[idx] = f2bf(v);
            }
        }
    }
}

// ---------------------------------------------------------------------------
// Flash attention, KV-parity split, 8-wave blocks.  R15 failed ONLY because
// __launch_bounds__(512,6) capped VGPR at 85 -> spill storm (FETCH/WRITE
// ~650 MB scratch).  Fixed: (512,4) -> VGPR cap 128 (fits, no spill),
// 16 waves/CU (2 blocks x 8 waves).  Everything else identical to the
// correctness-verified R15 source.
// ---------------------------------------------------------------------------
#define NP 32   // periods (64 keys each)

__global__ __launch_bounds__(512, 4) void attn_kernel(
        const unsigned short* __restrict__ ws, float* __restrict__ out)
{
    const unsigned short* Qw = ws;
    const unsigned short* Kw = ws + QKV_ELEMS;
    const unsigned short* Vw = ws + 2 * QKV_ELEMS;   // [b][h][d][s]

    // 512 blocks: 4 bh per XCD, 16 q-chunks of 128 per bh
    const int bid = blockIdx.x;
    const int idx = bid >> 3;                        // 0..63
    const int bh  = (bid & 7) * 4 + (idx >> 4);      // 0..31
    const int q0  = (idx & 15) * 128;

    // SMEM carve: K 4x2048 ush | V 4x2048 ush | Pu 8x512 u32 = 49152 B
    __shared__ __align__(16) unsigned short SMEM[24576];
    unsigned short* Kb = SMEM;               // + (t&3)*2048
    unsigned short* Vb = SMEM + 8192;        // + (t&3)*2048
    unsigned int*   Pb = (unsigned int*)(SMEM + 16384);

    const int tid  = threadIdx.x;
    const int wave = tid >> 6;                       // 0..7
    const int lane = tid & 63;
    const int l31  = lane & 31;
    const int half = lane >> 5;
    const int qsub = wave >> 1;                      // 0..3
    const int pw   = wave & 1;                       // KV parity

    const size_t base = (size_t)bh * S_LEN * HDIM;
    const int qrow = q0 + qsub * 32 + l31;

    // Q^T B-frags: lane = q-col l31, d-slots c*16 + half*8 + j
    bf16x8 qf[4];
#pragma unroll
    for (int c = 0; c < 4; ++c)
        qf[c] = *(const bf16x8*)(Qw + base + (size_t)qrow * HDIM + c * 16 + half * 8);

    bf16x8 ones;
    {
        u16x8 o;
#pragma unroll
        for (int e = 0; e < 8; ++e) o[e] = 0x3F80;
        ones = __builtin_bit_cast(bf16x8, o);
    }

    f32x16 Od0, Od1, Lacc;
#pragma unroll
    for (int i = 0; i < 16; ++i) { Od0[i] = 0.f; Od1[i] = 0.f; Lacc[i] = 0.f; }
    float mrun = -__builtin_inff();

    unsigned int* PuW = Pb + wave * 512;             // 16 rows x 32 q

    // staging coords: 512 threads cover 2 tiles (tid>>8 selects which).
    // K tile = [32 keys][64 d]; V tile = [64 d][32 s].
    const int stile = tid >> 8;                      // 0 or 1 (wave-uniform)
    const int t256  = tid & 255;
    const int ksrow = t256 >> 3;                     // 0..31
    const int ksg   = (t256 & 7) ^ (ksrow & 7);
    const int vrow  = t256 >> 2;                     // 0..63
    const int vsg   = (t256 & 3) ^ ((vrow >> 1) & 3);

    // hoisted read-side swizzled offsets
    int gk[4], gv[2];
#pragma unroll
    for (int c = 0; c < 4; ++c) gk[c] = ((c * 2 + half) ^ (l31 & 7)) * 8;
#pragma unroll
    for (int c = 0; c < 2; ++c) gv[c] = ((c * 2 + half) ^ ((l31 >> 1) & 3)) * 8;

    // prologue: stage tiles 0,1 (tile tt = stile)
    {
        const int tt = stile;
        gload_lds16(Kw + base + (size_t)(tt * 32 + ksrow) * HDIM + ksg * 8, &Kb[(tt & 3) * 2048 + t256 * 8]);
        gload_lds16(Vw + base + (size_t)vrow * S_LEN + tt * 32 + vsg * 8,   &Vb[(tt & 3) * 2048 + t256 * 8]);
    }
    __syncthreads();

    for (int p = 0; p < NP; ++p) {
        if (p < NP - 1) {
            const int tt = 2 * p + 2 + stile;
            gload_lds16(Kw + base + (size_t)(tt * 32 + ksrow) * HDIM + ksg * 8, &Kb[(tt & 3) * 2048 + t256 * 8]);
            gload_lds16(Vw + base + (size_t)vrow * S_LEN + tt * 32 + vsg * 8,   &Vb[(tt & 3) * 2048 + t256 * 8]);
        }

        const int tm = 2 * p + pw;                   // my parity's tile
        const unsigned short* Klds = &Kb[(tm & 3) * 2048];
        const unsigned short* Vlds = &Vb[(tm & 3) * 2048];

        // ---- QK: S^T = K(32 keys) . Q^T over d=64 ----
        f32x16 S;
#pragma unroll
        for (int i = 0; i < 16; ++i) S[i] = 0.f;
        __builtin_amdgcn_s_setprio(1);
#pragma unroll
        for (int c = 0; c < 4; ++c) {
            const bf16x8 ka = *(const bf16x8*)&Klds[l31 * 64 + gk[c]];
            S = __builtin_amdgcn_mfma_f32_32x32x16_bf16(ka, qf[c], S, 0, 0, 0);
        }
        __builtin_amdgcn_s_setprio(0);

        // ---- in-reg softmax (base 2), defer-max THR=8 ----
        float m8[8], m4[4];
#pragma unroll
        for (int i = 0; i < 8; ++i) m8[i] = fmaxf(S[i], S[i + 8]);
#pragma unroll
        for (int i = 0; i < 4; ++i) m4[i] = fmaxf(m8[i], m8[i + 4]);
        float mx = fmaxf(fmaxf(m4[0], m4[1]), fmaxf(m4[2], m4[3]));
        mx = fmaxf(mx, __shfl_xor(mx, 32, 64));      // other 16 keys

        if (!__all(mx - mrun <= 8.0f)) {
            const float mnew = fmaxf(mrun, mx);
            const float ex   = exp2f(mrun - mnew);
            mrun = mnew;
            Od0 *= ex;
            Od1 *= ex;
            Lacc *= ex;
        }

#pragma unroll
        for (int i = 0; i < 16; ++i) S[i] = exp2f(S[i] - mrun);

        // ---- P^T -> Pu key-pairs (C/D layout m74/m101: key=(r&3)+8(r>>2)+4h) ----
#pragma unroll
        for (int w = 0; w < 8; ++w) {
            const unsigned int pk = pack2(S[2 * w], S[2 * w + 1]);
            const int kp = (w & 1) + 4 * (w >> 1) + 2 * half;
            PuW[kp * 32 + l31] = pk;
        }
        __asm__ volatile("" ::: "memory");

        // ---- PV: O^T[d][q] += V^T.P^T ; Lacc += ones.P^T (k = 32 keys) ----
        __builtin_amdgcn_s_setprio(1);
#pragma unroll
        for (int c = 0; c < 2; ++c) {
            u32x4 pu;
#pragma unroll
            for (int e = 0; e < 4; ++e)
                pu[e] = PuW[(c * 8 + half * 4 + e) * 32 + l31];
            const bf16x8 pb = __builtin_bit_cast(bf16x8, pu);
            const bf16x8 va0 = *(const bf16x8*)&Vlds[l31 * 32 + gv[c]];
            const bf16x8 va1 = *(const bf16x8*)&Vlds[(32 + l31) * 32 + gv[c]];
            Od0  = __builtin_amdgcn_mfma_f32_32x32x16_bf16(va0,  pb, Od0,  0, 0, 0);
            Od1  = __builtin_amdgcn_mfma_f32_32x32x16_bf16(va1,  pb, Od1,  0, 0, 0);
            Lacc = __builtin_amdgcn_mfma_f32_32x32x16_bf16(ones, pb, Lacc, 0, 0, 0);
        }
        __builtin_amdgcn_s_setprio(0);

        __syncthreads();   // drains stage loads; rotates buffers
    }

    // ---- merge parity partials (exact): wave pair (qsub), lane-wise ----
    float* mrg = (float*)SMEM;                       // overlay (K/V dead)
    float* reg = mrg + qsub * 2176;                  // 64 m + 64 l + 2048 O
    if (pw) {
        reg[lane]      = mrun;
        reg[64 + lane] = Lacc[0];
#pragma unroll
        for (int i = 0; i < 16; ++i) {
            reg[128 + i * 64 + lane]        = Od0[i];
            reg[128 + (16 + i) * 64 + lane] = Od1[i];
        }
    }
    __syncthreads();
    if (!pw) {
        const float mb = reg[lane];
        const float lb = reg[64 + lane];
        const float ms = fmaxf(mrun, mb);
        const float sa = exp2f(mrun - ms);
        const float sb = exp2f(mb - ms);
        const float linv = 1.0f / (Lacc[0] * sa + lb * sb);

        const int bb = bh >> 4;
        const int hh = bh & 15;
        float* op = out + (size_t)qrow * (BATCH * DMODEL) + bb * DMODEL + hh * HDIM;
#pragma unroll
        for (int gg = 0; gg < 4; ++gg) {
            const int d0 = gg * 8 + half * 4;
            float4 v0, v1;
            v0.x = (Od0[gg * 4 + 0] * sa + reg[128 + (gg * 4 + 0) * 64 + lane] * sb) * linv;
            v0.y = (Od0[gg * 4 + 1] * sa + reg[128 + (gg * 4 + 1) * 64 + lane] * sb) * linv;
            v0.z = (Od0[gg * 4 + 2] * sa + reg[128 + (gg * 4 + 2) * 64 + lane] * sb) * linv;
            v0.w = (Od0[gg * 4 + 3] * sa + reg[128 + (gg * 4 + 3) * 64 + lane] * sb) * linv;
            v1.x = (Od1[gg * 4 + 0] * sa + reg[128 + (16 + gg * 4 + 0) * 64 + lane] * sb) * linv;
            v1.y = (Od1[gg * 4 + 1] * sa + reg[128 + (16 + gg * 4 + 1) * 64 + lane] * sb) * linv;
            v1.z = (Od1[gg * 4 + 2] * sa + reg[128 + (16 + gg * 4 + 2) * 64 + lane] * sb) * linv;
            v1.w = (Od1[gg * 4 + 3] * sa + reg[128 + (16 + gg * 4 + 3) * 64 + lane] * sb) * linv;
            *(float4*)(op + d0)      = v0;
            *(float4*)(op + 32 + d0) = v1;
        }
    }
}

extern "C" void kernel_launch(void* const* d_in, const int* in_sizes, int n_in,
                              void* d_out, int out_size, void* d_ws, size_t ws_size,
                              hipStream_t stream) {
    const float* q  = (const float*)d_in[0];
    const float* k  = (const float*)d_in[1];
    const float* v  = (const float*)d_in[2];
    const float* Wq = (const float*)d_in[3];
    const float* bq = (const float*)d_in[4];
    const float* Wk = (const float*)d_in[5];
    const float* bk = (const float*)d_in[6];
    const float* Wv = (const float*)d_in[7];
    const float* bv = (const float*)d_in[8];
    unsigned short* ws = (unsigned short*)d_ws;
    float* out = (float*)d_out;

    cvt_kernel<<<dim3(1024, 6), dim3(256), 0, stream>>>(q, k, v, Wq, Wk, Wv, ws);
    proj_kernel<<<dim3(768), dim3(256), 0, stream>>>(ws, bq, bk, bv, ws);
    attn_kernel<<<dim3(512), dim3(512), 0, stream>>>(ws, out);
}

// Round 17
// 133.551 us; speedup vs baseline: 3.2438x; 1.0051x over previous
//
#include <hip/hip_runtime.h>
#include <hip/hip_bf16.h>

#define S_LEN 2048
#define BATCH 2
#define DMODEL 1024
#define NHEAD 16
#define HDIM 64
#define MTOT (S_LEN * BATCH)
#define QKV_ELEMS ((size_t)MTOT * DMODEL)          // 4194304
#define XOFF (3 * QKV_ELEMS)                       // bf16 X' segment base (ushorts)
#define WOFF (XOFF + 3 * QKV_ELEMS)                // bf16 W' segment base
#define WSEG ((size_t)DMODEL * DMODEL)             // 1048576

typedef __bf16 bf16x8 __attribute__((ext_vector_type(8)));
typedef unsigned short u16x8 __attribute__((ext_vector_type(8)));
typedef float f32x4 __attribute__((ext_vector_type(4)));
typedef float f32x16 __attribute__((ext_vector_type(16)));
typedef unsigned int u32x4 __attribute__((ext_vector_type(4)));

__device__ __forceinline__ unsigned short f2bf(float f) {
    unsigned int u = __float_as_uint(f);
    u += 0x7FFFu + ((u >> 16) & 1u);
    return (unsigned short)(u >> 16);
}

// compiler-emitted v_cvt_pk_bf16_f32 (m240: do NOT hand-asm this).
__device__ __forceinline__ unsigned int pack2(float lo, float hi) {
    __hip_bfloat162 h = __float22bfloat162_rn(make_float2(lo, hi));
    unsigned int r;
    __builtin_memcpy(&r, &h, 4);
    return r;
}

__device__ __forceinline__ void gload_lds16(const void* g, void* l) {
    __builtin_amdgcn_global_load_lds(
        (const __attribute__((address_space(1))) unsigned int*)g,
        (__attribute__((address_space(3))) unsigned int*)l, 16, 0, 0);
}

// ---------------------------------------------------------------------------
// cvt_kernel (frozen): fp32 -> bf16 for X and W into ws.
// ---------------------------------------------------------------------------
__global__ __launch_bounds__(256) void cvt_kernel(
        const float* __restrict__ Xq, const float* __restrict__ Xk,
        const float* __restrict__ Xv, const float* __restrict__ Wq,
        const float* __restrict__ Wk, const float* __restrict__ Wv,
        unsigned short* __restrict__ ws)
{
    const int seg = blockIdx.y;
    const float* src;
    unsigned short* dst;
    int n4;
    if (seg < 3) {
        src = (seg == 0) ? Xq : (seg == 1) ? Xk : Xv;
        dst = ws + XOFF + (size_t)seg * QKV_ELEMS;
        n4  = (int)(QKV_ELEMS / 4);
    } else {
        const int s = seg - 3;
        src = (s == 0) ? Wq : (s == 1) ? Wk : Wv;
        dst = ws + WOFF + (size_t)s * WSEG;
        n4  = (int)(WSEG / 4);
    }
    const int stride = gridDim.x * blockDim.x;
    for (int i = blockIdx.x * blockDim.x + threadIdx.x; i < n4; i += stride) {
        const float4 v = ((const float4*)src)[i];
        uint2 o;
        o.x = pack2(v.x, v.y);
        o.y = pack2(v.z, v.w);
        ((uint2*)dst)[i] = o;
    }
}

// ---------------------------------------------------------------------------
// Projection GEMM (frozen — m97 structure on pre-converted bf16).
// Q: [b][h][s][d] scaled by 0.125*log2(e).  K: [b][h][s][d].  V: [b][h][d][s].
// ---------------------------------------------------------------------------
#define PBM 128
#define PBN 128
#define PBK 32
#define QSCALE 0.18033688011112042f   // 0.125 * log2(e)

__global__ __launch_bounds__(256, 3) void proj_kernel(
        const unsigned short* __restrict__ wsin,
        const float* __restrict__ bq, const float* __restrict__ bk,
        const float* __restrict__ bv, unsigned short* __restrict__ wsout)
{
    const int work = (blockIdx.x & 7) * 96 + (blockIdx.x >> 3);   // 0..767
    const int t    = work >> 8;
    const int rem  = work & 255;
    const int m0   = (rem >> 3) * PBM;
    const int n0   = (rem & 7) * PBN;

    const unsigned short* X = wsin + XOFF + (size_t)t * QKV_ELEMS;
    const unsigned short* W = wsin + WOFF + (size_t)t * WSEG;
    const float* bias = (t == 0) ? bq : (t == 1) ? bk : bv;
    unsigned short* out = wsout + (size_t)t * QKV_ELEMS;
    const float scale = (t == 0) ? QSCALE : 1.0f;

    __shared__ __align__(16) unsigned short Abuf[2][PBM * PBK];
    __shared__ __align__(16) unsigned short Bbuf[2][PBN * PBK];

    const int tid  = threadIdx.x;
    const int wave = tid >> 6;
    const int lane = tid & 63;
    const int lrow = lane & 15;
    const int lg   = lane >> 4;
    const int wr = (wave >> 1) * 64;
    const int wc = (wave & 1) * 64;

    f32x4 acc[4][4];
#pragma unroll
    for (int i = 0; i < 4; ++i)
#pragma unroll
        for (int j = 0; j < 4; ++j)
            acc[i][j] = (f32x4){0.f, 0.f, 0.f, 0.f};

    const int srow_ = tid >> 2;
    const int sc_   = tid & 3;
    const int gsw = (lg ^ (lrow & 3)) * 8;

#pragma unroll
    for (int i0 = 0; i0 < 2; ++i0) {
        const int row = i0 * 64 + srow_;
        const int c   = sc_ ^ (row & 3);
        gload_lds16(X + (size_t)(m0 + row) * DMODEL + c * 8, &Abuf[0][i0 * 2048 + tid * 8]);
        gload_lds16(W + (size_t)(n0 + row) * DMODEL + c * 8, &Bbuf[0][i0 * 2048 + tid * 8]);
    }
    __syncthreads();

    int cur = 0;
    for (int k0 = 0; k0 < DMODEL; k0 += PBK) {
        if (k0 + PBK < DMODEL) {
#pragma unroll
            for (int i0 = 0; i0 < 2; ++i0) {
                const int row = i0 * 64 + srow_;
                const int c   = sc_ ^ (row & 3);
                gload_lds16(X + (size_t)(m0 + row) * DMODEL + k0 + PBK + c * 8,
                            &Abuf[cur ^ 1][i0 * 2048 + tid * 8]);
                gload_lds16(W + (size_t)(n0 + row) * DMODEL + k0 + PBK + c * 8,
                            &Bbuf[cur ^ 1][i0 * 2048 + tid * 8]);
            }
        }

        bf16x8 af[4], bw[4];
#pragma unroll
        for (int i = 0; i < 4; ++i) {
            af[i] = *(const bf16x8*)&Abuf[cur][(wr + i * 16 + lrow) * PBK + gsw];
            bw[i] = *(const bf16x8*)&Bbuf[cur][(wc + i * 16 + lrow) * PBK + gsw];
        }
        __builtin_amdgcn_s_setprio(1);
#pragma unroll
        for (int i = 0; i < 4; ++i)
#pragma unroll
            for (int j = 0; j < 4; ++j)
                acc[i][j] = __builtin_amdgcn_mfma_f32_16x16x32_bf16(af[i], bw[j], acc[i][j], 0, 0, 0);
        __builtin_amdgcn_s_setprio(0);

        __syncthreads();
        cur ^= 1;
    }

#pragma unroll
    for (int j = 0; j < 4; ++j) {
        const int n  = n0 + wc + j * 16 + lrow;
        const float bv_ = bias[n];
        const int h  = n >> 6;
        const int dd = n & 63;
#pragma unroll
        for (int i = 0; i < 4; ++i) {
#pragma unroll
            for (int r = 0; r < 4; ++r) {
                const int m = m0 + wr + i * 16 + lg * 4 + r;
                const int s = m >> 1;
                const int b = m & 1;
                const float v = (acc[i][j][r] + bv_) * scale;
                size_t idx;
                if (t == 2)
                    idx = ((size_t)((b * NHEAD + h) * HDIM + dd)) * S_LEN + s;
                else
                    idx = ((size_t)((b * NHEAD + h) * S_LEN + s)) * HDIM + dd;
                out[idx] = f2bf(v);
            }
        }
    }
}

// ---------------------------------------------------------------------------
// Flash attention, KV-parity split, 8-wave blocks (R16 base, 79.4 us).
// This round: (1) Pu relayout [kp>>1][q][kp&1] -> b64 paired writes/reads
// (16 -> 8 DS ops per tile, 2-way bank aliasing = free); (2) max3 triplet
// max tree (15 -> 12 VALU).  All else identical to the passing R16 source.
// ---------------------------------------------------------------------------
#define NP 32   // periods (64 keys each)

__global__ __launch_bounds__(512, 4) void attn_kernel(
        const unsigned short* __restrict__ ws, float* __restrict__ out)
{
    const unsigned short* Qw = ws;
    const unsigned short* Kw = ws + QKV_ELEMS;
    const unsigned short* Vw = ws + 2 * QKV_ELEMS;   // [b][h][d][s]

    // 512 blocks: 4 bh per XCD, 16 q-chunks of 128 per bh
    const int bid = blockIdx.x;
    const int idx = bid >> 3;                        // 0..63
    const int bh  = (bid & 7) * 4 + (idx >> 4);      // 0..31
    const int q0  = (idx & 15) * 128;

    // SMEM carve: K 4x2048 ush | V 4x2048 ush | Pu 8x512 u32 = 49152 B
    __shared__ __align__(16) unsigned short SMEM[24576];
    unsigned short* Kb = SMEM;               // + (t&3)*2048
    unsigned short* Vb = SMEM + 8192;        // + (t&3)*2048
    unsigned int*   Pb = (unsigned int*)(SMEM + 16384);

    const int tid  = threadIdx.x;
    const int wave = tid >> 6;                       // 0..7
    const int lane = tid & 63;
    const int l31  = lane & 31;
    const int half = lane >> 5;
    const int qsub = wave >> 1;                      // 0..3
    const int pw   = wave & 1;                       // KV parity

    const size_t base = (size_t)bh * S_LEN * HDIM;
    const int qrow = q0 + qsub * 32 + l31;

    // Q^T B-frags: lane = q-col l31, d-slots c*16 + half*8 + j
    bf16x8 qf[4];
#pragma unroll
    for (int c = 0; c < 4; ++c)
        qf[c] = *(const bf16x8*)(Qw + base + (size_t)qrow * HDIM + c * 16 + half * 8);

    bf16x8 ones;
    {
        u16x8 o;
#pragma unroll
        for (int e = 0; e < 8; ++e) o[e] = 0x3F80;
        ones = __builtin_bit_cast(bf16x8, o);
    }

    f32x16 Od0, Od1, Lacc;
#pragma unroll
    for (int i = 0; i < 16; ++i) { Od0[i] = 0.f; Od1[i] = 0.f; Lacc[i] = 0.f; }
    float mrun = -__builtin_inff();

    // Pu: per-wave 8 rows x 64 u32 ([kp>>1][q][kp&1]); word kp holds keys
    // (2kp, 2kp+1) for q = l31.  b64-pair granularity throughout.
    unsigned int* PuW = Pb + wave * 512;

    // staging coords: 512 threads cover 2 tiles (tid>>8 selects which).
    // K tile = [32 keys][64 d]; V tile = [64 d][32 s].
    const int stile = tid >> 8;                      // 0 or 1 (wave-uniform)
    const int t256  = tid & 255;
    const int ksrow = t256 >> 3;                     // 0..31
    const int ksg   = (t256 & 7) ^ (ksrow & 7);
    const int vrow  = t256 >> 2;                     // 0..63
    const int vsg   = (t256 & 3) ^ ((vrow >> 1) & 3);

    // hoisted read-side swizzled offsets
    int gk[4], gv[2];
#pragma unroll
    for (int c = 0; c < 4; ++c) gk[c] = ((c * 2 + half) ^ (l31 & 7)) * 8;
#pragma unroll
    for (int c = 0; c < 2; ++c) gv[c] = ((c * 2 + half) ^ ((l31 >> 1) & 3)) * 8;

    // prologue: stage tiles 0,1 (tile tt = stile)
    {
        const int tt = stile;
        gload_lds16(Kw + base + (size_t)(tt * 32 + ksrow) * HDIM + ksg * 8, &Kb[(tt & 3) * 2048 + t256 * 8]);
        gload_lds16(Vw + base + (size_t)vrow * S_LEN + tt * 32 + vsg * 8,   &Vb[(tt & 3) * 2048 + t256 * 8]);
    }
    __syncthreads();

    for (int p = 0; p < NP; ++p) {
        if (p < NP - 1) {
            const int tt = 2 * p + 2 + stile;
            gload_lds16(Kw + base + (size_t)(tt * 32 + ksrow) * HDIM + ksg * 8, &Kb[(tt & 3) * 2048 + t256 * 8]);
            gload_lds16(Vw + base + (size_t)vrow * S_LEN + tt * 32 + vsg * 8,   &Vb[(tt & 3) * 2048 + t256 * 8]);
        }

        const int tm = 2 * p + pw;                   // my parity's tile
        const unsigned short* Klds = &Kb[(tm & 3) * 2048];
        const unsigned short* Vlds = &Vb[(tm & 3) * 2048];

        // ---- QK: S^T = K(32 keys) . Q^T over d=64 ----
        f32x16 S;
#pragma unroll
        for (int i = 0; i < 16; ++i) S[i] = 0.f;
        __builtin_amdgcn_s_setprio(1);
#pragma unroll
        for (int c = 0; c < 4; ++c) {
            const bf16x8 ka = *(const bf16x8*)&Klds[l31 * 64 + gk[c]];
            S = __builtin_amdgcn_mfma_f32_32x32x16_bf16(ka, qf[c], S, 0, 0, 0);
        }
        __builtin_amdgcn_s_setprio(0);

        // ---- in-reg softmax (base 2), defer-max THR=8, max3 tree ----
        float m8_[8];
#pragma unroll
        for (int i = 0; i < 8; ++i) m8_[i] = fmaxf(S[i], S[i + 8]);
        const float t0 = fmaxf(fmaxf(m8_[0], m8_[1]), m8_[2]);   // v_max3
        const float t1 = fmaxf(fmaxf(m8_[3], m8_[4]), m8_[5]);   // v_max3
        const float t2 = fmaxf(fmaxf(m8_[6], m8_[7]), t0);       // v_max3
        float mx = fmaxf(t1, t2);
        mx = fmaxf(mx, __shfl_xor(mx, 32, 64));      // other 16 keys

        if (!__all(mx - mrun <= 8.0f)) {
            const float mnew = fmaxf(mrun, mx);
            const float ex   = exp2f(mrun - mnew);
            mrun = mnew;
            Od0 *= ex;
            Od1 *= ex;
            Lacc *= ex;
        }

#pragma unroll
        for (int i = 0; i < 16; ++i) S[i] = exp2f(S[i] - mrun);

        // ---- P^T -> Pu, b64-paired (word kp=(w&1)+4(w>>1)+2h; rows kp>>1) ----
#pragma unroll
        for (int u = 0; u < 4; ++u) {
            uint2 two;
            two.x = pack2(S[4 * u],     S[4 * u + 1]);   // w=2u   -> kp=4u+2h
            two.y = pack2(S[4 * u + 2], S[4 * u + 3]);   // w=2u+1 -> kp=4u+2h+1
            *(uint2*)&PuW[(2 * u + half) * 64 + l31 * 2] = two;
        }
        __asm__ volatile("" ::: "memory");

        // ---- PV: O^T[d][q] += V^T.P^T ; Lacc += ones.P^T (k = 32 keys) ----
        __builtin_amdgcn_s_setprio(1);
#pragma unroll
        for (int c = 0; c < 2; ++c) {
            const int row0 = 4 * c + 2 * half;           // kp = c*8+4h+e rows
            const uint2 a = *(const uint2*)&PuW[row0 * 64 + l31 * 2];
            const uint2 b = *(const uint2*)&PuW[(row0 + 1) * 64 + l31 * 2];
            u32x4 pu; pu[0] = a.x; pu[1] = a.y; pu[2] = b.x; pu[3] = b.y;
            const bf16x8 pb = __builtin_bit_cast(bf16x8, pu);
            const bf16x8 va0 = *(const bf16x8*)&Vlds[l31 * 32 + gv[c]];
            const bf16x8 va1 = *(const bf16x8*)&Vlds[(32 + l31) * 32 + gv[c]];
            Od0  = __builtin_amdgcn_mfma_f32_32x32x16_bf16(va0,  pb, Od0,  0, 0, 0);
            Od1  = __builtin_amdgcn_mfma_f32_32x32x16_bf16(va1,  pb, Od1,  0, 0, 0);
            Lacc = __builtin_amdgcn_mfma_f32_32x32x16_bf16(ones, pb, Lacc, 0, 0, 0);
        }
        __builtin_amdgcn_s_setprio(0);

        __syncthreads();   // drains stage loads; rotates buffers
    }

    // ---- merge parity partials (exact): wave pair (qsub), lane-wise ----
    float* mrg = (float*)SMEM;                       // overlay (K/V dead)
    float* reg = mrg + qsub * 2176;                  // 64 m + 64 l + 2048 O
    if (pw) {
        reg[lane]      = mrun;
        reg[64 + lane] = Lacc[0];
#pragma unroll
        for (int i = 0; i < 16; ++i) {
            reg[128 + i * 64 + lane]        = Od0[i];
            reg[128 + (16 + i) * 64 + lane] = Od1[i];
        }
    }
    __syncthreads();
    if (!pw) {
        const float mb = reg[lane];
        const float lb = reg[64 + lane];
        const float ms = fmaxf(mrun, mb);
        const float sa = exp2f(mrun - ms);
        const float sb = exp2f(mb - ms);
        const float linv = 1.0f / (Lacc[0] * sa + lb * sb);

        const int bb = bh >> 4;
        const int hh = bh & 15;
        float* op = out + (size_t)qrow * (BATCH * DMODEL) + bb * DMODEL + hh * HDIM;
#pragma unroll
        for (int gg = 0; gg < 4; ++gg) {
            const int d0 = gg * 8 + half * 4;
            float4 v0, v1;
            v0.x = (Od0[gg * 4 + 0] * sa + reg[128 + (gg * 4 + 0) * 64 + lane] * sb) * linv;
            v0.y = (Od0[gg * 4 + 1] * sa + reg[128 + (gg * 4 + 1) * 64 + lane] * sb) * linv;
            v0.z = (Od0[gg * 4 + 2] * sa + reg[128 + (gg * 4 + 2) * 64 + lane] * sb) * linv;
            v0.w = (Od0[gg * 4 + 3] * sa + reg[128 + (gg * 4 + 3) * 64 + lane] * sb) * linv;
            v1.x = (Od1[gg * 4 + 0] * sa + reg[128 + (16 + gg * 4 + 0) * 64 + lane] * sb) * linv;
            v1.y = (Od1[gg * 4 + 1] * sa + reg[128 + (16 + gg * 4 + 1) * 64 + lane] * sb) * linv;
            v1.z = (Od1[gg * 4 + 2] * sa + reg[128 + (16 + gg * 4 + 2) * 64 + lane] * sb) * linv;
            v1.w = (Od1[gg * 4 + 3] * sa + reg[128 + (16 + gg * 4 + 3) * 64 + lane] * sb) * linv;
            *(float4*)(op + d0)      = v0;
            *(float4*)(op + 32 + d0) = v1;
        }
    }
}

extern "C" void kernel_launch(void* const* d_in, const int* in_sizes, int n_in,
                              void* d_out, int out_size, void* d_ws, size_t ws_size,
                              hipStream_t stream) {
    const float* q  = (const float*)d_in[0];
    const float* k  = (const float*)d_in[1];
    const float* v  = (const float*)d_in[2];
    const float* Wq = (const float*)d_in[3];
    const float* bq = (const float*)d_in[4];
    const float* Wk = (const float*)d_in[5];
    const float* bk = (const float*)d_in[6];
    const float* Wv = (const float*)d_in[7];
    const float* bv = (const float*)d_in[8];
    unsigned short* ws = (unsigned short*)d_ws;
    float* out = (float*)d_out;

    cvt_kernel<<<dim3(1024, 6), dim3(256), 0, stream>>>(q, k, v, Wq, Wk, Wv, ws);
    proj_kernel<<<dim3(768), dim3(256), 0, stream>>>(ws, bq, bk, bv, ws);
    attn_kernel<<<dim3(512), dim3(512), 0, stream>>>(ws, out);
}

// Round 18
// 131.415 us; speedup vs baseline: 3.2966x; 1.0163x over previous
//
#include <hip/hip_runtime.h>
#include <hip/hip_bf16.h>

#define S_LEN 2048
#define BATCH 2
#define DMODEL 1024
#define NHEAD 16
#define HDIM 64
#define MTOT (S_LEN * BATCH)
#define QKV_ELEMS ((size_t)MTOT * DMODEL)          // 4194304
#define XOFF (3 * QKV_ELEMS)                       // bf16 X' segment base (ushorts)
#define WOFF (XOFF + 3 * QKV_ELEMS)                // bf16 W' segment base
#define WSEG ((size_t)DMODEL * DMODEL)             // 1048576

typedef __bf16 bf16x8 __attribute__((ext_vector_type(8)));
typedef unsigned short u16x8 __attribute__((ext_vector_type(8)));
typedef float f32x4 __attribute__((ext_vector_type(4)));
typedef float f32x16 __attribute__((ext_vector_type(16)));
typedef unsigned int u32x4 __attribute__((ext_vector_type(4)));

__device__ __forceinline__ unsigned short f2bf(float f) {
    unsigned int u = __float_as_uint(f);
    u += 0x7FFFu + ((u >> 16) & 1u);
    return (unsigned short)(u >> 16);
}

// compiler-emitted v_cvt_pk_bf16_f32 (m240: do NOT hand-asm this).
__device__ __forceinline__ unsigned int pack2(float lo, float hi) {
    __hip_bfloat162 h = __float22bfloat162_rn(make_float2(lo, hi));
    unsigned int r;
    __builtin_memcpy(&r, &h, 4);
    return r;
}

__device__ __forceinline__ void gload_lds16(const void* g, void* l) {
    __builtin_amdgcn_global_load_lds(
        (const __attribute__((address_space(1))) unsigned int*)g,
        (__attribute__((address_space(3))) unsigned int*)l, 16, 0, 0);
}

// ---------------------------------------------------------------------------
// cvt_kernel (frozen): fp32 -> bf16 for X and W into ws.
// ---------------------------------------------------------------------------
__global__ __launch_bounds__(256) void cvt_kernel(
        const float* __restrict__ Xq, const float* __restrict__ Xk,
        const float* __restrict__ Xv, const float* __restrict__ Wq,
        const float* __restrict__ Wk, const float* __restrict__ Wv,
        unsigned short* __restrict__ ws)
{
    const int seg = blockIdx.y;
    const float* src;
    unsigned short* dst;
    int n4;
    if (seg < 3) {
        src = (seg == 0) ? Xq : (seg == 1) ? Xk : Xv;
        dst = ws + XOFF + (size_t)seg * QKV_ELEMS;
        n4  = (int)(QKV_ELEMS / 4);
    } else {
        const int s = seg - 3;
        src = (s == 0) ? Wq : (s == 1) ? Wk : Wv;
        dst = ws + WOFF + (size_t)s * WSEG;
        n4  = (int)(WSEG / 4);
    }
    const int stride = gridDim.x * blockDim.x;
    for (int i = blockIdx.x * blockDim.x + threadIdx.x; i < n4; i += stride) {
        const float4 v = ((const float4*)src)[i];
        uint2 o;
        o.x = pack2(v.x, v.y);
        o.y = pack2(v.z, v.w);
        ((uint2*)dst)[i] = o;
    }
}

// ---------------------------------------------------------------------------
// Projection GEMM (frozen — m97 structure on pre-converted bf16).
// Q: [b][h][s][d] scaled by 0.125*log2(e).  K: [b][h][s][d].  V: [b][h][d][s].
// ---------------------------------------------------------------------------
#define PBM 128
#define PBN 128
#define PBK 32
#define QSCALE 0.18033688011112042f   // 0.125 * log2(e)

__global__ __launch_bounds__(256, 3) void proj_kernel(
        const unsigned short* __restrict__ wsin,
        const float* __restrict__ bq, const float* __restrict__ bk,
        const float* __restrict__ bv, unsigned short* __restrict__ wsout)
{
    const int work = (blockIdx.x & 7) * 96 + (blockIdx.x >> 3);   // 0..767
    const int t    = work >> 8;
    const int rem  = work & 255;
    const int m0   = (rem >> 3) * PBM;
    const int n0   = (rem & 7) * PBN;

    const unsigned short* X = wsin + XOFF + (size_t)t * QKV_ELEMS;
    const unsigned short* W = wsin + WOFF + (size_t)t * WSEG;
    const float* bias = (t == 0) ? bq : (t == 1) ? bk : bv;
    unsigned short* out = wsout + (size_t)t * QKV_ELEMS;
    const float scale = (t == 0) ? QSCALE : 1.0f;

    __shared__ __align__(16) unsigned short Abuf[2][PBM * PBK];
    __shared__ __align__(16) unsigned short Bbuf[2][PBN * PBK];

    const int tid  = threadIdx.x;
    const int wave = tid >> 6;
    const int lane = tid & 63;
    const int lrow = lane & 15;
    const int lg   = lane >> 4;
    const int wr = (wave >> 1) * 64;
    const int wc = (wave & 1) * 64;

    f32x4 acc[4][4];
#pragma unroll
    for (int i = 0; i < 4; ++i)
#pragma unroll
        for (int j = 0; j < 4; ++j)
            acc[i][j] = (f32x4){0.f, 0.f, 0.f, 0.f};

    const int srow_ = tid >> 2;
    const int sc_   = tid & 3;
    const int gsw = (lg ^ (lrow & 3)) * 8;

#pragma unroll
    for (int i0 = 0; i0 < 2; ++i0) {
        const int row = i0 * 64 + srow_;
        const int c   = sc_ ^ (row & 3);
        gload_lds16(X + (size_t)(m0 + row) * DMODEL + c * 8, &Abuf[0][i0 * 2048 + tid * 8]);
        gload_lds16(W + (size_t)(n0 + row) * DMODEL + c * 8, &Bbuf[0][i0 * 2048 + tid * 8]);
    }
    __syncthreads();

    int cur = 0;
    for (int k0 = 0; k0 < DMODEL; k0 += PBK) {
        if (k0 + PBK < DMODEL) {
#pragma unroll
            for (int i0 = 0; i0 < 2; ++i0) {
                const int row = i0 * 64 + srow_;
                const int c   = sc_ ^ (row & 3);
                gload_lds16(X + (size_t)(m0 + row) * DMODEL + k0 + PBK + c * 8,
                            &Abuf[cur ^ 1][i0 * 2048 + tid * 8]);
                gload_lds16(W + (size_t)(n0 + row) * DMODEL + k0 + PBK + c * 8,
                            &Bbuf[cur ^ 1][i0 * 2048 + tid * 8]);
            }
        }

        bf16x8 af[4], bw[4];
#pragma unroll
        for (int i = 0; i < 4; ++i) {
            af[i] = *(const bf16x8*)&Abuf[cur][(wr + i * 16 + lrow) * PBK + gsw];
            bw[i] = *(const bf16x8*)&Bbuf[cur][(wc + i * 16 + lrow) * PBK + gsw];
        }
        __builtin_amdgcn_s_setprio(1);
#pragma unroll
        for (int i = 0; i < 4; ++i)
#pragma unroll
            for (int j = 0; j < 4; ++j)
                acc[i][j] = __builtin_amdgcn_mfma_f32_16x16x32_bf16(af[i], bw[j], acc[i][j], 0, 0, 0);
        __builtin_amdgcn_s_setprio(0);

        __syncthreads();
        cur ^= 1;
    }

#pragma unroll
    for (int j = 0; j < 4; ++j) {
        const int n  = n0 + wc + j * 16 + lrow;
        const float bv_ = bias[n];
        const int h  = n >> 6;
        const int dd = n & 63;
#pragma unroll
        for (int i = 0; i < 4; ++i) {
#pragma unroll
            for (int r = 0; r < 4; ++r) {
                const int m = m0 + wr + i * 16 + lg * 4 + r;
                const int s = m >> 1;
                const int b = m & 1;
                const float v = (acc[i][j][r] + bv_) * scale;
                size_t idx;
                if (t == 2)
                    idx = ((size_t)((b * NHEAD + h) * HDIM + dd)) * S_LEN + s;
                else
                    idx = ((size_t)((b * NHEAD + h) * S_LEN + s)) * HDIM + dd;
                out[idx] = f2bf(v);
            }
        }
    }
}

// ---------------------------------------------------------------------------
// Flash attention, KV-parity split, 8-wave blocks (R17 base, 78.0 us).
// This round: pre-shifted accumulator — init QK^T acc to -mrun so
// S = scores - mrun after MFMA; exp2 needs NO per-element subtract
// (-16 VALU/tile unconditional).  mrun starts at -30000 (finite; first
// tile rescale gives ex = exp2(-30000) = 0 cleanly).  Rescale branch:
// d = max(mxs,0); S -= d (rare path only); only Lacc[0] rescaled (the
// one component read).  All else identical to the passing R17 source.
// ---------------------------------------------------------------------------
#define NP 32   // periods (64 keys each)

__global__ __launch_bounds__(512, 4) void attn_kernel(
        const unsigned short* __restrict__ ws, float* __restrict__ out)
{
    const unsigned short* Qw = ws;
    const unsigned short* Kw = ws + QKV_ELEMS;
    const unsigned short* Vw = ws + 2 * QKV_ELEMS;   // [b][h][d][s]

    // 512 blocks: 4 bh per XCD, 16 q-chunks of 128 per bh
    const int bid = blockIdx.x;
    const int idx = bid >> 3;                        // 0..63
    const int bh  = (bid & 7) * 4 + (idx >> 4);      // 0..31
    const int q0  = (idx & 15) * 128;

    // SMEM carve: K 4x2048 ush | V 4x2048 ush | Pu 8x512 u32 = 49152 B
    __shared__ __align__(16) unsigned short SMEM[24576];
    unsigned short* Kb = SMEM;               // + (t&3)*2048
    unsigned short* Vb = SMEM + 8192;        // + (t&3)*2048
    unsigned int*   Pb = (unsigned int*)(SMEM + 16384);

    const int tid  = threadIdx.x;
    const int wave = tid >> 6;                       // 0..7
    const int lane = tid & 63;
    const int l31  = lane & 31;
    const int half = lane >> 5;
    const int qsub = wave >> 1;                      // 0..3
    const int pw   = wave & 1;                       // KV parity

    const size_t base = (size_t)bh * S_LEN * HDIM;
    const int qrow = q0 + qsub * 32 + l31;

    // Q^T B-frags: lane = q-col l31, d-slots c*16 + half*8 + j
    bf16x8 qf[4];
#pragma unroll
    for (int c = 0; c < 4; ++c)
        qf[c] = *(const bf16x8*)(Qw + base + (size_t)qrow * HDIM + c * 16 + half * 8);

    bf16x8 ones;
    {
        u16x8 o;
#pragma unroll
        for (int e = 0; e < 8; ++e) o[e] = 0x3F80;
        ones = __builtin_bit_cast(bf16x8, o);
    }

    f32x16 Od0, Od1, Lacc;
#pragma unroll
    for (int i = 0; i < 16; ++i) { Od0[i] = 0.f; Od1[i] = 0.f; Lacc[i] = 0.f; }
    float mrun = -30000.0f;   // finite sentinel: first-tile rescale -> ex = 0

    // Pu: per-wave 8 rows x 64 u32 ([kp>>1][q][kp&1]); b64-pair granularity.
    unsigned int* PuW = Pb + wave * 512;

    // staging coords: 512 threads cover 2 tiles (tid>>8 selects which).
    const int stile = tid >> 8;                      // 0 or 1 (wave-uniform)
    const int t256  = tid & 255;
    const int ksrow = t256 >> 3;                     // 0..31
    const int ksg   = (t256 & 7) ^ (ksrow & 7);
    const int vrow  = t256 >> 2;                     // 0..63
    const int vsg   = (t256 & 3) ^ ((vrow >> 1) & 3);

    // hoisted read-side swizzled offsets
    int gk[4], gv[2];
#pragma unroll
    for (int c = 0; c < 4; ++c) gk[c] = ((c * 2 + half) ^ (l31 & 7)) * 8;
#pragma unroll
    for (int c = 0; c < 2; ++c) gv[c] = ((c * 2 + half) ^ ((l31 >> 1) & 3)) * 8;

    // prologue: stage tiles 0,1 (tile tt = stile)
    {
        const int tt = stile;
        gload_lds16(Kw + base + (size_t)(tt * 32 + ksrow) * HDIM + ksg * 8, &Kb[(tt & 3) * 2048 + t256 * 8]);
        gload_lds16(Vw + base + (size_t)vrow * S_LEN + tt * 32 + vsg * 8,   &Vb[(tt & 3) * 2048 + t256 * 8]);
    }
    __syncthreads();

    for (int p = 0; p < NP; ++p) {
        if (p < NP - 1) {
            const int tt = 2 * p + 2 + stile;
            gload_lds16(Kw + base + (size_t)(tt * 32 + ksrow) * HDIM + ksg * 8, &Kb[(tt & 3) * 2048 + t256 * 8]);
            gload_lds16(Vw + base + (size_t)vrow * S_LEN + tt * 32 + vsg * 8,   &Vb[(tt & 3) * 2048 + t256 * 8]);
        }

        const int tm = 2 * p + pw;                   // my parity's tile
        const unsigned short* Klds = &Kb[(tm & 3) * 2048];
        const unsigned short* Vlds = &Vb[(tm & 3) * 2048];

        // ---- QK: S = K.Q^T - mrun (acc pre-initialized to -mrun) ----
        f32x16 S;
        const float nmrun = -mrun;
#pragma unroll
        for (int i = 0; i < 16; ++i) S[i] = nmrun;
        __builtin_amdgcn_s_setprio(1);
#pragma unroll
        for (int c = 0; c < 4; ++c) {
            const bf16x8 ka = *(const bf16x8*)&Klds[l31 * 64 + gk[c]];
            S = __builtin_amdgcn_mfma_f32_32x32x16_bf16(ka, qf[c], S, 0, 0, 0);
        }
        __builtin_amdgcn_s_setprio(0);

        // ---- in-reg softmax on SHIFTED scores (base 2), defer-max THR=8 ----
        float m8_[8];
#pragma unroll
        for (int i = 0; i < 8; ++i) m8_[i] = fmaxf(S[i], S[i + 8]);
        const float t0 = fmaxf(fmaxf(m8_[0], m8_[1]), m8_[2]);   // v_max3
        const float t1 = fmaxf(fmaxf(m8_[3], m8_[4]), m8_[5]);   // v_max3
        const float t2 = fmaxf(fmaxf(m8_[6], m8_[7]), t0);       // v_max3
        float mxs = fmaxf(t1, t2);
        mxs = fmaxf(mxs, __shfl_xor(mxs, 32, 64));   // other 16 keys (shifted max)

        if (!__all(mxs <= 8.0f)) {                   // defer-max on shifted value
            const float d  = fmaxf(mxs, 0.0f);       // mnew - mrun
            const float ex = exp2f(-d);
            mrun += d;
#pragma unroll
            for (int i = 0; i < 16; ++i) S[i] -= d;  // rare path only
            Od0 *= ex;
            Od1 *= ex;
            Lacc[0] *= ex;                           // only component ever read
        }

#pragma unroll
        for (int i = 0; i < 16; ++i) S[i] = exp2f(S[i]);   // no subtract!

        // ---- P^T -> Pu, b64-paired (word kp=(w&1)+4(w>>1)+2h; rows kp>>1) ----
#pragma unroll
        for (int u = 0; u < 4; ++u) {
            uint2 two;
            two.x = pack2(S[4 * u],     S[4 * u + 1]);   // w=2u   -> kp=4u+2h
            two.y = pack2(S[4 * u + 2], S[4 * u + 3]);   // w=2u+1 -> kp=4u+2h+1
            *(uint2*)&PuW[(2 * u + half) * 64 + l31 * 2] = two;
        }
        __asm__ volatile("" ::: "memory");

        // ---- PV: O^T[d][q] += V^T.P^T ; Lacc += ones.P^T (k = 32 keys) ----
        __builtin_amdgcn_s_setprio(1);
#pragma unroll
        for (int c = 0; c < 2; ++c) {
            const int row0 = 4 * c + 2 * half;           // kp = c*8+4h+e rows
            const uint2 a = *(const uint2*)&PuW[row0 * 64 + l31 * 2];
            const uint2 b = *(const uint2*)&PuW[(row0 + 1) * 64 + l31 * 2];
            u32x4 pu; pu[0] = a.x; pu[1] = a.y; pu[2] = b.x; pu[3] = b.y;
            const bf16x8 pb = __builtin_bit_cast(bf16x8, pu);
            const bf16x8 va0 = *(const bf16x8*)&Vlds[l31 * 32 + gv[c]];
            const bf16x8 va1 = *(const bf16x8*)&Vlds[(32 + l31) * 32 + gv[c]];
            Od0  = __builtin_amdgcn_mfma_f32_32x32x16_bf16(va0,  pb, Od0,  0, 0, 0);
            Od1  = __builtin_amdgcn_mfma_f32_32x32x16_bf16(va1,  pb, Od1,  0, 0, 0);
            Lacc = __builtin_amdgcn_mfma_f32_32x32x16_bf16(ones, pb, Lacc, 0, 0, 0);
        }
        __builtin_amdgcn_s_setprio(0);

        __syncthreads();   // drains stage loads; rotates buffers
    }

    // ---- merge parity partials (exact): wave pair (qsub), lane-wise ----
    float* mrg = (float*)SMEM;                       // overlay (K/V dead)
    float* reg = mrg + qsub * 2176;                  // 64 m + 64 l + 2048 O
    if (pw) {
        reg[lane]      = mrun;
        reg[64 + lane] = Lacc[0];
#pragma unroll
        for (int i = 0; i < 16; ++i) {
            reg[128 + i * 64 + lane]        = Od0[i];
            reg[128 + (16 + i) * 64 + lane] = Od1[i];
        }
    }
    __syncthreads();
    if (!pw) {
        const float mb = reg[lane];
        const float lb = reg[64 + lane];
        const float ms = fmaxf(mrun, mb);
        const float sa = exp2f(mrun - ms);
        const float sb = exp2f(mb - ms);
        const float linv = 1.0f / (Lacc[0] * sa + lb * sb);

        const int bb = bh >> 4;
        const int hh = bh & 15;
        float* op = out + (size_t)qrow * (BATCH * DMODEL) + bb * DMODEL + hh * HDIM;
#pragma unroll
        for (int gg = 0; gg < 4; ++gg) {
            const int d0 = gg * 8 + half * 4;
            float4 v0, v1;
            v0.x = (Od0[gg * 4 + 0] * sa + reg[128 + (gg * 4 + 0) * 64 + lane] * sb) * linv;
            v0.y = (Od0[gg * 4 + 1] * sa + reg[128 + (gg * 4 + 1) * 64 + lane] * sb) * linv;
            v0.z = (Od0[gg * 4 + 2] * sa + reg[128 + (gg * 4 + 2) * 64 + lane] * sb) * linv;
            v0.w = (Od0[gg * 4 + 3] * sa + reg[128 + (gg * 4 + 3) * 64 + lane] * sb) * linv;
            v1.x = (Od1[gg * 4 + 0] * sa + reg[128 + (16 + gg * 4 + 0) * 64 + lane] * sb) * linv;
            v1.y = (Od1[gg * 4 + 1] * sa + reg[128 + (16 + gg * 4 + 1) * 64 + lane] * sb) * linv;
            v1.z = (Od1[gg * 4 + 2] * sa + reg[128 + (16 + gg * 4 + 2) * 64 + lane] * sb) * linv;
            v1.w = (Od1[gg * 4 + 3] * sa + reg[128 + (16 + gg * 4 + 3) * 64 + lane] * sb) * linv;
            *(float4*)(op + d0)      = v0;
            *(float4*)(op + 32 + d0) = v1;
        }
    }
}

extern "C" void kernel_launch(void* const* d_in, const int* in_sizes, int n_in,
                              void* d_out, int out_size, void* d_ws, size_t ws_size,
                              hipStream_t stream) {
    const float* q  = (const float*)d_in[0];
    const float* k  = (const float*)d_in[1];
    const float* v  = (const float*)d_in[2];
    const float* Wq = (const float*)d_in[3];
    const float* bq = (const float*)d_in[4];
    const float* Wk = (const float*)d_in[5];
    const float* bk = (const float*)d_in[6];
    const float* Wv = (const float*)d_in[7];
    const float* bv = (const float*)d_in[8];
    unsigned short* ws = (unsigned short*)d_ws;
    float* out = (float*)d_out;

    cvt_kernel<<<dim3(1024, 6), dim3(256), 0, stream>>>(q, k, v, Wq, Wk, Wv, ws);
    proj_kernel<<<dim3(768), dim3(256), 0, stream>>>(ws, bq, bk, bv, ws);
    attn_kernel<<<dim3(512), dim3(512), 0, stream>>>(ws, out);
}